// Round 1
// baseline (3346.832 us; speedup 1.0000x reference)
//
#include <hip/hip_runtime.h>
#include <cfloat>

#define Nn 2048
#define KK 20
#define BB 8
#define SLOPE 0.2f

// ---------------- small transpose: At[c][r] = A[r][c] ----------------
__global__ void transpose_kernel(const float* __restrict__ A, float* __restrict__ At,
                                 int R, int C) {
    int i = blockIdx.x * 256 + threadIdx.x;
    if (i < R * C) {
        int r = i / C, c = i - r * C;
        At[(long)c * R + r] = A[i];
    }
}

// ---------------- KNN: 4 rows per block, 256 threads ----------------
template<int C>
__global__ void knn_kernel(const float* __restrict__ x, long bstride,
                           int* __restrict__ idx) {
    __shared__ float ctr[4][C];
    __shared__ float dist[4][Nn];
    const int tid = threadIdx.x;
    const int b = blockIdx.x / (Nn / 4);
    const int n0 = (blockIdx.x % (Nn / 4)) * 4;
    const float* xb = x + (long)b * bstride;

    for (int t = tid; t < 4 * C; t += 256) {
        int r = t / C, c = t - r * C;
        ctr[r][c] = xb[(long)c * Nn + (n0 + r)];
    }
    __syncthreads();

    for (int j0 = 0; j0 < Nn; j0 += 256) {
        int j = j0 + tid;
        float a0 = 0.f, a1 = 0.f, a2 = 0.f, a3 = 0.f;
        #pragma unroll 4
        for (int c = 0; c < C; ++c) {
            float v = xb[(long)c * Nn + j];
            float d0 = ctr[0][c] - v; a0 += d0 * d0;
            float d1 = ctr[1][c] - v; a1 += d1 * d1;
            float d2 = ctr[2][c] - v; a2 += d2 * d2;
            float d3 = ctr[3][c] - v; a3 += d3 * d3;
        }
        dist[0][j] = a0; dist[1][j] = a1; dist[2][j] = a2; dist[3][j] = a3;
    }
    __syncthreads();

    // each wave owns one row; iterative argmin (lowest index on ties)
    const int wid = tid >> 6;
    const int lane = tid & 63;
    float* drow = dist[wid];
    int* outp = idx + ((long)b * Nn + (n0 + wid)) * KK;
    for (int k = 0; k < KK; ++k) {
        float best = FLT_MAX;
        int bi = Nn;
        for (int j = lane; j < Nn; j += 64) {
            float v = drow[j];
            if (v < best) { best = v; bi = j; }
        }
        #pragma unroll
        for (int s = 32; s > 0; s >>= 1) {
            float ov = __shfl_down(best, s);
            int   oi = __shfl_down(bi, s);
            if (ov < best || (ov == best && oi < bi)) { best = ov; bi = oi; }
        }
        bi = __shfl(bi, 0);
        if (lane == 0) outp[k] = bi;
        drow[bi] = FLT_MAX;   // all lanes write same value to same address
    }
}

// ---------------- Edge conv + leaky + max over K ----------------
// Wt layout: [2*C_IN][C_out] (transposed). OPT output channels per thread.
template<int C_IN, int OPT>
__global__ void edge_conv_kernel(const float* __restrict__ x, long bstride,
                                 const int* __restrict__ idx,
                                 const float* __restrict__ Wt, int C_out,
                                 float* __restrict__ out, long obstride) {
    __shared__ float nbr[KK][C_IN];
    __shared__ float ctr[C_IN];
    __shared__ int ji[KK];
    const int tid = threadIdx.x;
    const int BD = blockDim.x;
    const int b = blockIdx.x >> 11;
    const int n = blockIdx.x & (Nn - 1);
    const float* xb = x + (long)b * bstride;

    if (tid < KK) ji[tid] = idx[((long)b * Nn + n) * KK + tid];
    for (int c = tid; c < C_IN; c += BD) ctr[c] = xb[(long)c * Nn + n];
    __syncthreads();
    for (int t = tid; t < KK * C_IN; t += BD) {
        int k = t / C_IN, c = t - k * C_IN;
        nbr[k][c] = xb[(long)c * Nn + ji[k]];
    }
    __syncthreads();

    // bias_o = sum_c (W[o,C+c] - W[o,c]) * ctr[c]
    float bias[OPT];
    #pragma unroll
    for (int t = 0; t < OPT; ++t) {
        int o = tid + t * BD;
        float s = 0.f;
        for (int c = 0; c < C_IN; ++c) {
            float cc = ctr[c];
            s += Wt[(long)(C_IN + c) * C_out + o] * cc - Wt[(long)c * C_out + o] * cc;
        }
        bias[t] = s;
    }

    float acc[OPT][KK];
    #pragma unroll
    for (int t = 0; t < OPT; ++t)
        #pragma unroll
        for (int k = 0; k < KK; ++k) acc[t][k] = bias[t];

    if constexpr (C_IN % 4 == 0) {
        for (int c4 = 0; c4 < C_IN / 4; ++c4) {
            float w0[OPT], w1[OPT], w2[OPT], w3[OPT];
            #pragma unroll
            for (int t = 0; t < OPT; ++t) {
                int o = tid + t * BD;
                w0[t] = Wt[(long)(4 * c4 + 0) * C_out + o];
                w1[t] = Wt[(long)(4 * c4 + 1) * C_out + o];
                w2[t] = Wt[(long)(4 * c4 + 2) * C_out + o];
                w3[t] = Wt[(long)(4 * c4 + 3) * C_out + o];
            }
            #pragma unroll
            for (int k = 0; k < KK; ++k) {
                float4 v = *(const float4*)(&nbr[k][4 * c4]);
                #pragma unroll
                for (int t = 0; t < OPT; ++t)
                    acc[t][k] += w0[t] * v.x + w1[t] * v.y + w2[t] * v.z + w3[t] * v.w;
            }
        }
    } else {
        for (int c = 0; c < C_IN; ++c) {
            float w[OPT];
            #pragma unroll
            for (int t = 0; t < OPT; ++t) w[t] = Wt[(long)c * C_out + tid + t * BD];
            #pragma unroll
            for (int k = 0; k < KK; ++k) {
                float v = nbr[k][c];
                #pragma unroll
                for (int t = 0; t < OPT; ++t) acc[t][k] += w[t] * v;
            }
        }
    }

    #pragma unroll
    for (int t = 0; t < OPT; ++t) {
        float best = -FLT_MAX;
        #pragma unroll
        for (int k = 0; k < KK; ++k) {
            float y = acc[t][k];
            y = y > 0.f ? y : SLOPE * y;
            best = fmaxf(best, y);
        }
        out[(long)b * obstride + (long)(tid + t * BD) * Nn + n] = best;
    }
}

// ---------------- Global conv + leaky + max over N ----------------
// grid: B*128 blocks; 256 threads = 8 o x 32 n-lanes; float4 over n.
__global__ void global_kernel(const float* __restrict__ xcat,
                              const float* __restrict__ Wg,
                              float* __restrict__ out) {
    const int tid = threadIdx.x;
    const int oi = tid >> 5;
    const int ni = tid & 31;
    const int b = blockIdx.x >> 7;
    const int o = ((blockIdx.x & 127) << 3) + oi;
    const float* xb = xcat + (long)b * 512 * Nn;
    const float* wrow = Wg + (long)o * 512;

    float m0 = -FLT_MAX, m1 = -FLT_MAX, m2 = -FLT_MAX, m3 = -FLT_MAX;
    for (int n4 = ni; n4 < Nn / 4; n4 += 32) {
        float a0 = 0.f, a1 = 0.f, a2 = 0.f, a3 = 0.f;
        const float* xp = xb + 4 * n4;
        #pragma unroll 4
        for (int c = 0; c < 512; ++c) {
            float w = wrow[c];
            float4 v = *(const float4*)(xp + (long)c * Nn);
            a0 += w * v.x; a1 += w * v.y; a2 += w * v.z; a3 += w * v.w;
        }
        a0 = a0 > 0.f ? a0 : SLOPE * a0;
        a1 = a1 > 0.f ? a1 : SLOPE * a1;
        a2 = a2 > 0.f ? a2 : SLOPE * a2;
        a3 = a3 > 0.f ? a3 : SLOPE * a3;
        m0 = fmaxf(m0, a0); m1 = fmaxf(m1, a1);
        m2 = fmaxf(m2, a2); m3 = fmaxf(m3, a3);
    }
    float best = fmaxf(fmaxf(m0, m1), fmaxf(m2, m3));
    #pragma unroll
    for (int s = 16; s > 0; s >>= 1)
        best = fmaxf(best, __shfl_xor(best, s, 32));
    if (ni == 0) out[(long)b * 1024 + o] = best;
}

extern "C" void kernel_launch(void* const* d_in, const int* in_sizes, int n_in,
                              void* d_out, int out_size, void* d_ws, size_t ws_size,
                              hipStream_t stream) {
    const float* x  = (const float*)d_in[0];
    const float* W1 = (const float*)d_in[1];   // [64][6]
    const float* W2 = (const float*)d_in[2];   // [64][128]
    const float* W3 = (const float*)d_in[3];   // [128][128]
    const float* W4 = (const float*)d_in[4];   // [256][256]
    const float* Wg = (const float*)d_in[5];   // [1024][512]
    float* out = (float*)d_out;

    float* ws = (float*)d_ws;
    float* xcat = ws;                                   // 8*512*2048
    int*   idxb = (int*)(ws + (long)BB * 512 * Nn);     // 8*2048*20
    float* wt1  = ws + (long)BB * 512 * Nn + (long)BB * Nn * KK;
    float* wt2  = wt1 + 6 * 64;
    float* wt3  = wt2 + 128 * 64;
    float* wt4  = wt3 + 128 * 128;

    const long XB = (long)512 * Nn;   // xcat batch stride

    transpose_kernel<<<(64 * 6 + 255) / 256, 256, 0, stream>>>(W1, wt1, 64, 6);
    transpose_kernel<<<(64 * 128 + 255) / 256, 256, 0, stream>>>(W2, wt2, 64, 128);
    transpose_kernel<<<(128 * 128 + 255) / 256, 256, 0, stream>>>(W3, wt3, 128, 128);
    transpose_kernel<<<(256 * 256 + 255) / 256, 256, 0, stream>>>(W4, wt4, 256, 256);

    const int knn_grid = BB * Nn / 4;
    const int ec_grid  = BB * Nn;

    // block1: x (C=3) -> xcat[0:64]
    knn_kernel<3><<<knn_grid, 256, 0, stream>>>(x, (long)3 * Nn, idxb);
    edge_conv_kernel<3, 1><<<ec_grid, 64, 0, stream>>>(x, (long)3 * Nn, idxb, wt1, 64,
                                                       xcat, XB);
    // block2: xcat[0:64] -> xcat[64:128]
    knn_kernel<64><<<knn_grid, 256, 0, stream>>>(xcat, XB, idxb);
    edge_conv_kernel<64, 1><<<ec_grid, 64, 0, stream>>>(xcat, XB, idxb, wt2, 64,
                                                        xcat + (long)64 * Nn, XB);
    // block3: xcat[64:128] -> xcat[128:256]
    knn_kernel<64><<<knn_grid, 256, 0, stream>>>(xcat + (long)64 * Nn, XB, idxb);
    edge_conv_kernel<64, 2><<<ec_grid, 64, 0, stream>>>(xcat + (long)64 * Nn, XB, idxb,
                                                        wt3, 128,
                                                        xcat + (long)128 * Nn, XB);
    // block4: xcat[128:256] -> xcat[256:512]
    knn_kernel<128><<<knn_grid, 256, 0, stream>>>(xcat + (long)128 * Nn, XB, idxb);
    edge_conv_kernel<128, 2><<<ec_grid, 128, 0, stream>>>(xcat + (long)128 * Nn, XB, idxb,
                                                          wt4, 256,
                                                          xcat + (long)256 * Nn, XB);
    // global
    global_kernel<<<BB * 128, 256, 0, stream>>>(xcat, Wg, out);
}

// Round 2
// 2197.042 us; speedup vs baseline: 1.5233x; 1.5233x over previous
//
#include <hip/hip_runtime.h>
#include <cfloat>

#define Nn 2048
#define KK 20
#define BB 8
#define SLOPE 0.2f

// ---------------- small transpose: At[c][r] = A[r][c] ----------------
__global__ void transpose_kernel(const float* __restrict__ A, float* __restrict__ At,
                                 int R, int C) {
    int i = blockIdx.x * 256 + threadIdx.x;
    if (i < R * C) {
        int r = i / C, c = i - r * C;
        At[(long)c * R + r] = A[i];
    }
}

// ---------------- KNN: 4 rows per block, 256 threads ----------------
template<int C>
__global__ void knn_kernel(const float* __restrict__ x, long bstride,
                           int* __restrict__ idx) {
    __shared__ float ctr[4][C];
    __shared__ float dist[4][Nn];
    const int tid = threadIdx.x;
    const int b = blockIdx.x / (Nn / 4);
    const int n0 = (blockIdx.x % (Nn / 4)) * 4;
    const float* xb = x + (long)b * bstride;

    for (int t = tid; t < 4 * C; t += 256) {
        int r = t / C, c = t - r * C;
        ctr[r][c] = xb[(long)c * Nn + (n0 + r)];
    }
    __syncthreads();

    for (int j0 = 0; j0 < Nn; j0 += 256) {
        int j = j0 + tid;
        float a0 = 0.f, a1 = 0.f, a2 = 0.f, a3 = 0.f;
        #pragma unroll 4
        for (int c = 0; c < C; ++c) {
            float v = xb[(long)c * Nn + j];
            float d0 = ctr[0][c] - v; a0 += d0 * d0;
            float d1 = ctr[1][c] - v; a1 += d1 * d1;
            float d2 = ctr[2][c] - v; a2 += d2 * d2;
            float d3 = ctr[3][c] - v; a3 += d3 * d3;
        }
        dist[0][j] = a0; dist[1][j] = a1; dist[2][j] = a2; dist[3][j] = a3;
    }
    __syncthreads();

    // each wave owns one row; iterative argmin via u64 (bits<<32|idx) keys
    const int wid = tid >> 6;
    const int lane = tid & 63;
    float* drow = dist[wid];
    int* outp = idx + ((long)b * Nn + (n0 + wid)) * KK;
    for (int k = 0; k < KK; ++k) {
        unsigned long long best = ~0ull;
        #pragma unroll
        for (int jj = 0; jj < Nn / 256; ++jj) {
            int j4 = (jj * 64 + lane) * 4;
            float4 v = *(const float4*)(&drow[j4]);
            unsigned long long k0 = ((unsigned long long)__float_as_uint(v.x) << 32) | (unsigned)(j4 + 0);
            unsigned long long k1 = ((unsigned long long)__float_as_uint(v.y) << 32) | (unsigned)(j4 + 1);
            unsigned long long k2 = ((unsigned long long)__float_as_uint(v.z) << 32) | (unsigned)(j4 + 2);
            unsigned long long k3 = ((unsigned long long)__float_as_uint(v.w) << 32) | (unsigned)(j4 + 3);
            unsigned long long m01 = k0 < k1 ? k0 : k1;
            unsigned long long m23 = k2 < k3 ? k2 : k3;
            unsigned long long m = m01 < m23 ? m01 : m23;
            best = m < best ? m : best;
        }
        #pragma unroll
        for (int s = 32; s > 0; s >>= 1) {
            unsigned long long ob = __shfl_xor(best, s, 64);
            best = ob < best ? ob : best;
        }
        int bi = (int)(best & 0xffffffffull);
        if (lane == 0) {
            outp[k] = bi;
            drow[bi] = FLT_MAX;
        }
    }
}

// ---------------- Edge conv + leaky + max over K ----------------
// Wt layout: [2*C_IN][C_out] (transposed). OPT output channels per thread.
template<int C_IN, int OPT>
__global__ void edge_conv_kernel(const float* __restrict__ x, long bstride,
                                 const int* __restrict__ idx,
                                 const float* __restrict__ Wt, int C_out,
                                 float* __restrict__ out, long obstride) {
    __shared__ float nbr[KK][C_IN];
    __shared__ float ctr[C_IN];
    __shared__ int ji[KK];
    const int tid = threadIdx.x;
    const int BD = blockDim.x;
    const int b = blockIdx.x >> 11;
    const int n = blockIdx.x & (Nn - 1);
    const float* xb = x + (long)b * bstride;

    if (tid < KK) ji[tid] = idx[((long)b * Nn + n) * KK + tid];
    for (int c = tid; c < C_IN; c += BD) ctr[c] = xb[(long)c * Nn + n];
    __syncthreads();
    for (int t = tid; t < KK * C_IN; t += BD) {
        int k = t / C_IN, c = t - k * C_IN;
        nbr[k][c] = xb[(long)c * Nn + ji[k]];
    }
    __syncthreads();

    // bias_o = sum_c (W[o,C+c] - W[o,c]) * ctr[c]
    float bias[OPT];
    #pragma unroll
    for (int t = 0; t < OPT; ++t) {
        int o = tid + t * BD;
        float s = 0.f;
        for (int c = 0; c < C_IN; ++c) {
            float cc = ctr[c];
            s += Wt[(long)(C_IN + c) * C_out + o] * cc - Wt[(long)c * C_out + o] * cc;
        }
        bias[t] = s;
    }

    float acc[OPT][KK];
    #pragma unroll
    for (int t = 0; t < OPT; ++t)
        #pragma unroll
        for (int k = 0; k < KK; ++k) acc[t][k] = bias[t];

    if constexpr (C_IN % 4 == 0) {
        for (int c4 = 0; c4 < C_IN / 4; ++c4) {
            float w0[OPT], w1[OPT], w2[OPT], w3[OPT];
            #pragma unroll
            for (int t = 0; t < OPT; ++t) {
                int o = tid + t * BD;
                w0[t] = Wt[(long)(4 * c4 + 0) * C_out + o];
                w1[t] = Wt[(long)(4 * c4 + 1) * C_out + o];
                w2[t] = Wt[(long)(4 * c4 + 2) * C_out + o];
                w3[t] = Wt[(long)(4 * c4 + 3) * C_out + o];
            }
            #pragma unroll
            for (int k = 0; k < KK; ++k) {
                float4 v = *(const float4*)(&nbr[k][4 * c4]);
                #pragma unroll
                for (int t = 0; t < OPT; ++t)
                    acc[t][k] += w0[t] * v.x + w1[t] * v.y + w2[t] * v.z + w3[t] * v.w;
            }
        }
    } else {
        for (int c = 0; c < C_IN; ++c) {
            float w[OPT];
            #pragma unroll
            for (int t = 0; t < OPT; ++t) w[t] = Wt[(long)c * C_out + tid + t * BD];
            #pragma unroll
            for (int k = 0; k < KK; ++k) {
                float v = nbr[k][c];
                #pragma unroll
                for (int t = 0; t < OPT; ++t) acc[t][k] += w[t] * v;
            }
        }
    }

    #pragma unroll
    for (int t = 0; t < OPT; ++t) {
        float best = -FLT_MAX;
        #pragma unroll
        for (int k = 0; k < KK; ++k) {
            float y = acc[t][k];
            y = y > 0.f ? y : SLOPE * y;
            best = fmaxf(best, y);
        }
        out[(long)b * obstride + (long)(tid + t * BD) * Nn + n] = best;
    }
}

// ---------------- Global conv: register-blocked partial-max ----------------
// grid: B * 16 o-tiles(64) * 8 n-chunks(256) = 1024 blocks; 256 thr = 8 og x 32 ni
// thread: o = ot*64 + og*8 + t (t=0..7), n = ch*256 + p*128 + ni*4 + j
__global__ void __launch_bounds__(256)
global_kernel(const float* __restrict__ xcat,
              const float* __restrict__ WgT,   // [512][1024]
              float* __restrict__ partial) {   // [B][1024][8]
    const int tid = threadIdx.x;
    const int og = tid >> 5;
    const int ni = tid & 31;
    const int b  = blockIdx.x >> 7;
    const int r  = blockIdx.x & 127;
    const int ot = r >> 3;
    const int ch = r & 7;
    const int obase = ot * 64 + og * 8;
    const float* xb = xcat + (long)b * 512 * Nn + ch * 256;

    float m[8];
    #pragma unroll
    for (int t = 0; t < 8; ++t) m[t] = -FLT_MAX;

    for (int p = 0; p < 2; ++p) {
        float acc[8][4];
        #pragma unroll
        for (int t = 0; t < 8; ++t)
            #pragma unroll
            for (int j = 0; j < 4; ++j) acc[t][j] = 0.f;
        const float* xp = xb + p * 128 + ni * 4;
        #pragma unroll 2
        for (int c = 0; c < 512; ++c) {
            float4 w0 = *(const float4*)(WgT + (long)c * 1024 + obase);
            float4 w1 = *(const float4*)(WgT + (long)c * 1024 + obase + 4);
            float4 v  = *(const float4*)(xp + (long)c * Nn);
            acc[0][0] += w0.x * v.x; acc[0][1] += w0.x * v.y; acc[0][2] += w0.x * v.z; acc[0][3] += w0.x * v.w;
            acc[1][0] += w0.y * v.x; acc[1][1] += w0.y * v.y; acc[1][2] += w0.y * v.z; acc[1][3] += w0.y * v.w;
            acc[2][0] += w0.z * v.x; acc[2][1] += w0.z * v.y; acc[2][2] += w0.z * v.z; acc[2][3] += w0.z * v.w;
            acc[3][0] += w0.w * v.x; acc[3][1] += w0.w * v.y; acc[3][2] += w0.w * v.z; acc[3][3] += w0.w * v.w;
            acc[4][0] += w1.x * v.x; acc[4][1] += w1.x * v.y; acc[4][2] += w1.x * v.z; acc[4][3] += w1.x * v.w;
            acc[5][0] += w1.y * v.x; acc[5][1] += w1.y * v.y; acc[5][2] += w1.y * v.z; acc[5][3] += w1.y * v.w;
            acc[6][0] += w1.z * v.x; acc[6][1] += w1.z * v.y; acc[6][2] += w1.z * v.z; acc[6][3] += w1.z * v.w;
            acc[7][0] += w1.w * v.x; acc[7][1] += w1.w * v.y; acc[7][2] += w1.w * v.z; acc[7][3] += w1.w * v.w;
        }
        #pragma unroll
        for (int t = 0; t < 8; ++t) {
            float mm = fmaxf(fmaxf(acc[t][0], acc[t][1]), fmaxf(acc[t][2], acc[t][3]));
            m[t] = fmaxf(m[t], mm);
        }
    }
    // reduce over the 32 ni lanes (same o within each 32-lane group)
    #pragma unroll
    for (int t = 0; t < 8; ++t) {
        float v = m[t];
        #pragma unroll
        for (int s = 16; s > 0; s >>= 1)
            v = fmaxf(v, __shfl_xor(v, s, 32));
        m[t] = v;
    }
    if (ni == 0) {
        #pragma unroll
        for (int t = 0; t < 8; ++t)
            partial[((long)b * 1024 + obase + t) * 8 + ch] = m[t];
    }
}

// ---------------- final max over n-chunks + leaky ----------------
__global__ void gmax_kernel(const float* __restrict__ partial, float* __restrict__ out) {
    int i = blockIdx.x * 256 + threadIdx.x;   // 0..8191
    float m = -FLT_MAX;
    #pragma unroll
    for (int j = 0; j < 8; ++j) m = fmaxf(m, partial[(long)i * 8 + j]);
    out[i] = m > 0.f ? m : SLOPE * m;
}

extern "C" void kernel_launch(void* const* d_in, const int* in_sizes, int n_in,
                              void* d_out, int out_size, void* d_ws, size_t ws_size,
                              hipStream_t stream) {
    const float* x  = (const float*)d_in[0];
    const float* W1 = (const float*)d_in[1];   // [64][6]
    const float* W2 = (const float*)d_in[2];   // [64][128]
    const float* W3 = (const float*)d_in[3];   // [128][128]
    const float* W4 = (const float*)d_in[4];   // [256][256]
    const float* Wg = (const float*)d_in[5];   // [1024][512]
    float* out = (float*)d_out;

    float* ws = (float*)d_ws;
    float* xcat = ws;                                   // 8*512*2048
    int*   idxb = (int*)(ws + (long)BB * 512 * Nn);     // 8*2048*20
    float* wt1  = ws + (long)BB * 512 * Nn + (long)BB * Nn * KK;
    float* wt2  = wt1 + 6 * 64;
    float* wt3  = wt2 + 128 * 64;
    float* wt4  = wt3 + 128 * 128;
    float* wgt  = wt4 + 256 * 256;                      // 512*1024
    float* part = wgt + 512 * 1024;                     // 8*1024*8

    const long XB = (long)512 * Nn;   // xcat batch stride

    transpose_kernel<<<(64 * 6 + 255) / 256, 256, 0, stream>>>(W1, wt1, 64, 6);
    transpose_kernel<<<(64 * 128 + 255) / 256, 256, 0, stream>>>(W2, wt2, 64, 128);
    transpose_kernel<<<(128 * 128 + 255) / 256, 256, 0, stream>>>(W3, wt3, 128, 128);
    transpose_kernel<<<(256 * 256 + 255) / 256, 256, 0, stream>>>(W4, wt4, 256, 256);
    transpose_kernel<<<(1024 * 512 + 255) / 256, 256, 0, stream>>>(Wg, wgt, 1024, 512);

    const int knn_grid = BB * Nn / 4;
    const int ec_grid  = BB * Nn;

    // block1: x (C=3) -> xcat[0:64]
    knn_kernel<3><<<knn_grid, 256, 0, stream>>>(x, (long)3 * Nn, idxb);
    edge_conv_kernel<3, 1><<<ec_grid, 64, 0, stream>>>(x, (long)3 * Nn, idxb, wt1, 64,
                                                       xcat, XB);
    // block2: xcat[0:64] -> xcat[64:128]
    knn_kernel<64><<<knn_grid, 256, 0, stream>>>(xcat, XB, idxb);
    edge_conv_kernel<64, 1><<<ec_grid, 64, 0, stream>>>(xcat, XB, idxb, wt2, 64,
                                                        xcat + (long)64 * Nn, XB);
    // block3: xcat[64:128] -> xcat[128:256]
    knn_kernel<64><<<knn_grid, 256, 0, stream>>>(xcat + (long)64 * Nn, XB, idxb);
    edge_conv_kernel<64, 2><<<ec_grid, 64, 0, stream>>>(xcat + (long)64 * Nn, XB, idxb,
                                                        wt3, 128,
                                                        xcat + (long)128 * Nn, XB);
    // block4: xcat[128:256] -> xcat[256:512]
    knn_kernel<128><<<knn_grid, 256, 0, stream>>>(xcat + (long)128 * Nn, XB, idxb);
    edge_conv_kernel<128, 2><<<ec_grid, 128, 0, stream>>>(xcat + (long)128 * Nn, XB, idxb,
                                                          wt4, 256,
                                                          xcat + (long)256 * Nn, XB);
    // global conv (partial) + final max
    global_kernel<<<BB * 128, 256, 0, stream>>>(xcat, wgt, part);
    gmax_kernel<<<BB * 1024 / 256, 256, 0, stream>>>(part, out);
}

// Round 3
// 1487.115 us; speedup vs baseline: 2.2506x; 1.4774x over previous
//
#include <hip/hip_runtime.h>
#include <cfloat>

#define Nn 2048
#define KK 20
#define BB 8
#define SLOPE 0.2f

// ---------------- small transpose: At[c][r] = A[r][c] ----------------
__global__ void transpose_kernel(const float* __restrict__ A, float* __restrict__ At,
                                 int R, int C) {
    int i = blockIdx.x * 256 + threadIdx.x;
    if (i < R * C) {
        int r = i / C, c = i - r * C;
        At[(long)c * R + r] = A[i];
    }
}

// ---------------- weight stack: Wstk[c][o] = W[o][c]; Wstk[c][Co+o] = W[o][C+c]-W[o][c]
__global__ void wstack_kernel(const float* __restrict__ W, float* __restrict__ Wstk,
                              int Co, int C) {
    int i = blockIdx.x * 256 + threadIdx.x;
    if (i < Co * C) {
        int o = i / C, c = i - o * C;
        float a = W[(long)o * 2 * C + c];
        float bb = W[(long)o * 2 * C + C + c];
        Wstk[(long)c * 2 * Co + o] = a;
        Wstk[(long)c * 2 * Co + Co + o] = bb - a;
    }
}

// ---------------- KNN: 4 rows per block, 256 threads ----------------
template<int C>
__global__ void knn_kernel(const float* __restrict__ x, long bstride,
                           int* __restrict__ idx) {
    __shared__ float ctr[4][C];
    __shared__ float dist[4][Nn];
    const int tid = threadIdx.x;
    const int b = blockIdx.x / (Nn / 4);
    const int n0 = (blockIdx.x % (Nn / 4)) * 4;
    const float* xb = x + (long)b * bstride;

    for (int t = tid; t < 4 * C; t += 256) {
        int r = t / C, c = t - r * C;
        ctr[r][c] = xb[(long)c * Nn + (n0 + r)];
    }
    __syncthreads();

    for (int j0 = 0; j0 < Nn; j0 += 256) {
        int j = j0 + tid;
        float a0 = 0.f, a1 = 0.f, a2 = 0.f, a3 = 0.f;
        #pragma unroll 4
        for (int c = 0; c < C; ++c) {
            float v = xb[(long)c * Nn + j];
            float d0 = ctr[0][c] - v; a0 += d0 * d0;
            float d1 = ctr[1][c] - v; a1 += d1 * d1;
            float d2 = ctr[2][c] - v; a2 += d2 * d2;
            float d3 = ctr[3][c] - v; a3 += d3 * d3;
        }
        dist[0][j] = a0; dist[1][j] = a1; dist[2][j] = a2; dist[3][j] = a3;
    }
    __syncthreads();

    // each wave owns one row; iterative argmin via u64 (bits<<32|idx) keys
    const int wid = tid >> 6;
    const int lane = tid & 63;
    float* drow = dist[wid];
    int* outp = idx + ((long)b * Nn + (n0 + wid)) * KK;
    for (int k = 0; k < KK; ++k) {
        unsigned long long best = ~0ull;
        #pragma unroll
        for (int jj = 0; jj < Nn / 256; ++jj) {
            int j4 = (jj * 64 + lane) * 4;
            float4 v = *(const float4*)(&drow[j4]);
            unsigned long long k0 = ((unsigned long long)__float_as_uint(v.x) << 32) | (unsigned)(j4 + 0);
            unsigned long long k1 = ((unsigned long long)__float_as_uint(v.y) << 32) | (unsigned)(j4 + 1);
            unsigned long long k2 = ((unsigned long long)__float_as_uint(v.z) << 32) | (unsigned)(j4 + 2);
            unsigned long long k3 = ((unsigned long long)__float_as_uint(v.w) << 32) | (unsigned)(j4 + 3);
            unsigned long long m01 = k0 < k1 ? k0 : k1;
            unsigned long long m23 = k2 < k3 ? k2 : k3;
            unsigned long long m = m01 < m23 ? m01 : m23;
            best = m < best ? m : best;
        }
        #pragma unroll
        for (int s = 32; s > 0; s >>= 1) {
            unsigned long long ob = __shfl_xor(best, s, 64);
            best = ob < best ? ob : best;
        }
        int bi = (int)(best & 0xffffffffull);
        if (lane == 0) {
            outp[k] = bi;
            drow[bi] = FLT_MAX;
        }
    }
}

// ---------------- projection GEMM: Z[m][0..2Co) = sum_c x[c][m] * Wstk[c][.] ----
// grid = 8 b * 32 mtiles * (CO2/64) otiles; block 256; thread = 4m x 4o
template<int CIN, int CO2>
__global__ void __launch_bounds__(256)
proj_gemm(const float* __restrict__ x, long bst,
          const float* __restrict__ Wstk, float* __restrict__ Z) {
    const int tid = threadIdx.x;
    const int b  = blockIdx.x & 7;
    const int mt = (blockIdx.x >> 3) & 31;
    const int ot = blockIdx.x >> 8;
    const int mi = mt * 64 + (tid & 15) * 4;
    const int oj = ot * 64 + (tid >> 4) * 4;
    const float* xb = x + (long)b * bst + mi;

    float acc[4][4];
    #pragma unroll
    for (int r = 0; r < 4; ++r)
        #pragma unroll
        for (int j = 0; j < 4; ++j) acc[r][j] = 0.f;

    #pragma unroll 4
    for (int c = 0; c < CIN; ++c) {
        float4 xv = *(const float4*)(xb + (long)c * Nn);
        float4 wv = *(const float4*)(Wstk + (long)c * CO2 + oj);
        acc[0][0] += xv.x * wv.x; acc[0][1] += xv.x * wv.y; acc[0][2] += xv.x * wv.z; acc[0][3] += xv.x * wv.w;
        acc[1][0] += xv.y * wv.x; acc[1][1] += xv.y * wv.y; acc[1][2] += xv.y * wv.z; acc[1][3] += xv.y * wv.w;
        acc[2][0] += xv.z * wv.x; acc[2][1] += xv.z * wv.y; acc[2][2] += xv.z * wv.z; acc[2][3] += xv.z * wv.w;
        acc[3][0] += xv.w * wv.x; acc[3][1] += xv.w * wv.y; acc[3][2] += xv.w * wv.z; acc[3][3] += xv.w * wv.w;
    }
    float* Zb = Z + (long)b * 2048 * CO2;
    #pragma unroll
    for (int r = 0; r < 4; ++r) {
        float4 v = make_float4(acc[r][0], acc[r][1], acc[r][2], acc[r][3]);
        *(float4*)(Zb + (long)(mi + r) * CO2 + oj) = v;
    }
}

// ---------------- gather-max epilogue ----------------
// out[o][n] = leaky( Zc[n][o] + max_k Zn[idx[n,k]][o] )
// block: 16 n x 256 thr (4 waves x 4 n each); LDS transpose for coalesced store.
template<int CO>
__global__ void __launch_bounds__(256)
gather_max(const float* __restrict__ Z, const int* __restrict__ idx,
           float* __restrict__ out, long obst) {
    constexpr int CO2 = 2 * CO;
    constexpr int VEC = CO / 64;
    __shared__ float tile[16][CO + 4];
    __shared__ int ji[16][KK];
    const int tid = threadIdx.x;
    const int b  = blockIdx.x & 7;
    const int n0 = (blockIdx.x >> 3) * 16;
    const float* Zb = Z + (long)b * 2048 * CO2;

    for (int t = tid; t < 16 * KK; t += 256) {
        int nn = t / KK, k = t - nn * KK;
        ji[nn][k] = idx[((long)b * Nn + n0 + nn) * KK + k];
    }
    __syncthreads();

    const int w = tid >> 6, lane = tid & 63;
    for (int i = 0; i < 4; ++i) {
        int nl = w * 4 + i, n = n0 + nl;
        float mx[VEC];
        #pragma unroll
        for (int v = 0; v < VEC; ++v) mx[v] = -FLT_MAX;
        for (int k = 0; k < KK; ++k) {
            int m = ji[nl][k];
            const float* zr = Zb + (long)m * CO2 + lane * VEC;
            #pragma unroll
            for (int v = 0; v < VEC; ++v) mx[v] = fmaxf(mx[v], zr[v]);
        }
        const float* zc = Zb + (long)n * CO2 + CO + lane * VEC;
        #pragma unroll
        for (int v = 0; v < VEC; ++v) {
            float y = mx[v] + zc[v];
            tile[nl][lane * VEC + v] = y > 0.f ? y : SLOPE * y;
        }
    }
    __syncthreads();

    for (int r = tid; r < CO * 4; r += 256) {
        int o = r >> 2, q = r & 3;
        float4 vv;
        vv.x = tile[q * 4 + 0][o];
        vv.y = tile[q * 4 + 1][o];
        vv.z = tile[q * 4 + 2][o];
        vv.w = tile[q * 4 + 3][o];
        *(float4*)(out + (long)b * obst + (long)o * Nn + n0 + q * 4) = vv;
    }
}

// ---------------- Global conv: register-blocked partial-max ----------------
__global__ void __launch_bounds__(256)
global_kernel(const float* __restrict__ xcat,
              const float* __restrict__ WgT,   // [512][1024]
              float* __restrict__ partial) {   // [B][1024][8]
    const int tid = threadIdx.x;
    const int og = tid >> 5;
    const int ni = tid & 31;
    const int b  = blockIdx.x >> 7;
    const int r  = blockIdx.x & 127;
    const int ot = r >> 3;
    const int ch = r & 7;
    const int obase = ot * 64 + og * 8;
    const float* xb = xcat + (long)b * 512 * Nn + ch * 256;

    float m[8];
    #pragma unroll
    for (int t = 0; t < 8; ++t) m[t] = -FLT_MAX;

    for (int p = 0; p < 2; ++p) {
        float acc[8][4];
        #pragma unroll
        for (int t = 0; t < 8; ++t)
            #pragma unroll
            for (int j = 0; j < 4; ++j) acc[t][j] = 0.f;
        const float* xp = xb + p * 128 + ni * 4;
        #pragma unroll 2
        for (int c = 0; c < 512; ++c) {
            float4 w0 = *(const float4*)(WgT + (long)c * 1024 + obase);
            float4 w1 = *(const float4*)(WgT + (long)c * 1024 + obase + 4);
            float4 v  = *(const float4*)(xp + (long)c * Nn);
            acc[0][0] += w0.x * v.x; acc[0][1] += w0.x * v.y; acc[0][2] += w0.x * v.z; acc[0][3] += w0.x * v.w;
            acc[1][0] += w0.y * v.x; acc[1][1] += w0.y * v.y; acc[1][2] += w0.y * v.z; acc[1][3] += w0.y * v.w;
            acc[2][0] += w0.z * v.x; acc[2][1] += w0.z * v.y; acc[2][2] += w0.z * v.z; acc[2][3] += w0.z * v.w;
            acc[3][0] += w0.w * v.x; acc[3][1] += w0.w * v.y; acc[3][2] += w0.w * v.z; acc[3][3] += w0.w * v.w;
            acc[4][0] += w1.x * v.x; acc[4][1] += w1.x * v.y; acc[4][2] += w1.x * v.z; acc[4][3] += w1.x * v.w;
            acc[5][0] += w1.y * v.x; acc[5][1] += w1.y * v.y; acc[5][2] += w1.y * v.z; acc[5][3] += w1.y * v.w;
            acc[6][0] += w1.z * v.x; acc[6][1] += w1.z * v.y; acc[6][2] += w1.z * v.z; acc[6][3] += w1.z * v.w;
            acc[7][0] += w1.w * v.x; acc[7][1] += w1.w * v.y; acc[7][2] += w1.w * v.z; acc[7][3] += w1.w * v.w;
        }
        #pragma unroll
        for (int t = 0; t < 8; ++t) {
            float mm = fmaxf(fmaxf(acc[t][0], acc[t][1]), fmaxf(acc[t][2], acc[t][3]));
            m[t] = fmaxf(m[t], mm);
        }
    }
    #pragma unroll
    for (int t = 0; t < 8; ++t) {
        float v = m[t];
        #pragma unroll
        for (int s = 16; s > 0; s >>= 1)
            v = fmaxf(v, __shfl_xor(v, s, 32));
        m[t] = v;
    }
    if (ni == 0) {
        #pragma unroll
        for (int t = 0; t < 8; ++t)
            partial[((long)b * 1024 + obase + t) * 8 + ch] = m[t];
    }
}

// ---------------- final max over n-chunks + leaky ----------------
__global__ void gmax_kernel(const float* __restrict__ partial, float* __restrict__ out) {
    int i = blockIdx.x * 256 + threadIdx.x;   // 0..8191
    float m = -FLT_MAX;
    #pragma unroll
    for (int j = 0; j < 8; ++j) m = fmaxf(m, partial[(long)i * 8 + j]);
    out[i] = m > 0.f ? m : SLOPE * m;
}

extern "C" void kernel_launch(void* const* d_in, const int* in_sizes, int n_in,
                              void* d_out, int out_size, void* d_ws, size_t ws_size,
                              hipStream_t stream) {
    const float* x  = (const float*)d_in[0];
    const float* W1 = (const float*)d_in[1];   // [64][6]
    const float* W2 = (const float*)d_in[2];   // [64][128]
    const float* W3 = (const float*)d_in[3];   // [128][128]
    const float* W4 = (const float*)d_in[4];   // [256][256]
    const float* Wg = (const float*)d_in[5];   // [1024][512]
    float* out = (float*)d_out;

    float* ws = (float*)d_ws;
    float* xcat = ws;                                   // 8*512*2048
    int*   idxb = (int*)(xcat + (long)BB * 512 * Nn);   // 8*2048*20 ints
    float* wgt  = (float*)(idxb + (long)BB * Nn * KK);  // 512*1024
    float* part = wgt + 512 * 1024;                     // 8*1024*8
    float* ws1  = part + BB * 1024 * 8;                 // 3*128
    float* ws2  = ws1 + 3 * 128;                        // 64*128
    float* ws3  = ws2 + 64 * 128;                       // 64*256
    float* ws4  = ws3 + 64 * 256;                       // 128*512
    float* Z    = ws4 + 128 * 512;                      // 8*2048*512

    const long XB = (long)512 * Nn;   // xcat batch stride

    transpose_kernel<<<(1024 * 512 + 255) / 256, 256, 0, stream>>>(Wg, wgt, 1024, 512);
    wstack_kernel<<<(64 * 3 + 255) / 256, 256, 0, stream>>>(W1, ws1, 64, 3);
    wstack_kernel<<<(64 * 64 + 255) / 256, 256, 0, stream>>>(W2, ws2, 64, 64);
    wstack_kernel<<<(128 * 64 + 255) / 256, 256, 0, stream>>>(W3, ws3, 128, 64);
    wstack_kernel<<<(256 * 128 + 255) / 256, 256, 0, stream>>>(W4, ws4, 256, 128);

    const int knn_grid = BB * Nn / 4;
    const int ep_grid  = (Nn / 16) * BB;   // 1024

    // stage 1: x (C=3) -> xcat[0:64]
    knn_kernel<3><<<knn_grid, 256, 0, stream>>>(x, (long)3 * Nn, idxb);
    proj_gemm<3, 128><<<8 * 32 * 2, 256, 0, stream>>>(x, (long)3 * Nn, ws1, Z);
    gather_max<64><<<ep_grid, 256, 0, stream>>>(Z, idxb, xcat, XB);
    // stage 2: xcat[0:64] -> xcat[64:128]
    knn_kernel<64><<<knn_grid, 256, 0, stream>>>(xcat, XB, idxb);
    proj_gemm<64, 128><<<8 * 32 * 2, 256, 0, stream>>>(xcat, XB, ws2, Z);
    gather_max<64><<<ep_grid, 256, 0, stream>>>(Z, idxb, xcat + (long)64 * Nn, XB);
    // stage 3: xcat[64:128] -> xcat[128:256]
    knn_kernel<64><<<knn_grid, 256, 0, stream>>>(xcat + (long)64 * Nn, XB, idxb);
    proj_gemm<64, 256><<<8 * 32 * 4, 256, 0, stream>>>(xcat + (long)64 * Nn, XB, ws3, Z);
    gather_max<128><<<ep_grid, 256, 0, stream>>>(Z, idxb, xcat + (long)128 * Nn, XB);
    // stage 4: xcat[128:256] -> xcat[256:512]
    knn_kernel<128><<<knn_grid, 256, 0, stream>>>(xcat + (long)128 * Nn, XB, idxb);
    proj_gemm<128, 512><<<8 * 32 * 8, 256, 0, stream>>>(xcat + (long)128 * Nn, XB, ws4, Z);
    gather_max<256><<<ep_grid, 256, 0, stream>>>(Z, idxb, xcat + (long)256 * Nn, XB);

    // global conv (partial) + final max
    global_kernel<<<BB * 128, 256, 0, stream>>>(xcat, wgt, part);
    gmax_kernel<<<BB * 1024 / 256, 256, 0, stream>>>(part, out);
}

// Round 4
// 1151.546 us; speedup vs baseline: 2.9064x; 1.2914x over previous
//
#include <hip/hip_runtime.h>
#include <cfloat>

#define Nn 2048
#define KK 20
#define BB 8
#define SLOPE 0.2f
#define NCH 16   // n-chunks in global conv

// ---------------- small transpose: At[c][r] = A[r][c] ----------------
__global__ void transpose_kernel(const float* __restrict__ A, float* __restrict__ At,
                                 int R, int C) {
    int i = blockIdx.x * 256 + threadIdx.x;
    if (i < R * C) {
        int r = i / C, c = i - r * C;
        At[(long)c * R + r] = A[i];
    }
}

// ---------------- weight stack: Wstk[c][o] = W[o][c]; Wstk[c][Co+o] = W[o][C+c]-W[o][c]
__global__ void wstack_kernel(const float* __restrict__ W, float* __restrict__ Wstk,
                              int Co, int C) {
    int i = blockIdx.x * 256 + threadIdx.x;
    if (i < Co * C) {
        int o = i / C, c = i - o * C;
        float a = W[(long)o * 2 * C + c];
        float bb = W[(long)o * 2 * C + C + c];
        Wstk[(long)c * 2 * Co + o] = a;
        Wstk[(long)c * 2 * Co + Co + o] = bb - a;
    }
}

// order-preserving float-bits -> u32 map (works for negatives)
__device__ __forceinline__ unsigned fkey(float f) {
    unsigned u = __float_as_uint(f);
    return u ^ (((unsigned)((int)u >> 31)) | 0x80000000u);
}

// ---------------- KNN: 8 rows per block, 512 threads ----------------
// dist order == xx_j - 2*dot(x_n, x_j)  (per-row const xx_n dropped: order-invariant)
template<int C>
__global__ void __launch_bounds__(512)
knn_kernel(const float* __restrict__ x, long bstride, int* __restrict__ idx) {
    __shared__ unsigned dist[8][Nn];   // XOR-mapped float keys; 64 KB exactly
    const int tid = threadIdx.x;
    const int b  = blockIdx.x >> 8;         // Nn/8 = 256 blocks per b
    const int n0 = (blockIdx.x & 255) * 8;
    const float* xb = x + (long)b * bstride;

    // distance phase: thread owns j = q*512 + tid, q = 0..3
    float acc[8][4];
    #pragma unroll
    for (int r = 0; r < 8; ++r)
        #pragma unroll
        for (int q = 0; q < 4; ++q) acc[r][q] = 0.f;
    float sq[4] = {0.f, 0.f, 0.f, 0.f};

    #pragma unroll 4
    for (int c = 0; c < C; ++c) {
        const float* xp = xb + (long)c * Nn;
        float xv0 = xp[tid];
        float xv1 = xp[tid + 512];
        float xv2 = xp[tid + 1024];
        float xv3 = xp[tid + 1536];
        // centers: 8 contiguous floats at n0 (uniform address -> broadcast, L1-hot)
        float4 c0 = *(const float4*)(xp + n0);
        float4 c1 = *(const float4*)(xp + n0 + 4);
        sq[0] += xv0 * xv0; sq[1] += xv1 * xv1; sq[2] += xv2 * xv2; sq[3] += xv3 * xv3;
        acc[0][0] += c0.x * xv0; acc[0][1] += c0.x * xv1; acc[0][2] += c0.x * xv2; acc[0][3] += c0.x * xv3;
        acc[1][0] += c0.y * xv0; acc[1][1] += c0.y * xv1; acc[1][2] += c0.y * xv2; acc[1][3] += c0.y * xv3;
        acc[2][0] += c0.z * xv0; acc[2][1] += c0.z * xv1; acc[2][2] += c0.z * xv2; acc[2][3] += c0.z * xv3;
        acc[3][0] += c0.w * xv0; acc[3][1] += c0.w * xv1; acc[3][2] += c0.w * xv2; acc[3][3] += c0.w * xv3;
        acc[4][0] += c1.x * xv0; acc[4][1] += c1.x * xv1; acc[4][2] += c1.x * xv2; acc[4][3] += c1.x * xv3;
        acc[5][0] += c1.y * xv0; acc[5][1] += c1.y * xv1; acc[5][2] += c1.y * xv2; acc[5][3] += c1.y * xv3;
        acc[6][0] += c1.z * xv0; acc[6][1] += c1.z * xv1; acc[6][2] += c1.z * xv2; acc[6][3] += c1.z * xv3;
        acc[7][0] += c1.w * xv0; acc[7][1] += c1.w * xv1; acc[7][2] += c1.w * xv2; acc[7][3] += c1.w * xv3;
    }
    #pragma unroll
    for (int r = 0; r < 8; ++r) {
        #pragma unroll
        for (int q = 0; q < 4; ++q) {
            float d = fmaf(-2.f, acc[r][q], sq[q]);
            dist[r][q * 512 + tid] = fkey(d);
        }
    }
    __syncthreads();

    // selection: wave w owns row w; per-lane min in regs, winner-only rescan
    const int w = tid >> 6, lane = tid & 63;
    unsigned* drow = dist[w];
    int* outp = idx + ((long)b * Nn + n0 + w) * KK;

    auto scan = [&]() -> unsigned long long {
        unsigned long long m = ~0ull;
        #pragma unroll
        for (int jj = 0; jj < 8; ++jj) {
            int j4 = (jj * 64 + lane) * 4;
            uint4 v = *(const uint4*)(drow + j4);
            unsigned long long k0 = ((unsigned long long)v.x << 32) | (unsigned)(j4 + 0);
            unsigned long long k1 = ((unsigned long long)v.y << 32) | (unsigned)(j4 + 1);
            unsigned long long k2 = ((unsigned long long)v.z << 32) | (unsigned)(j4 + 2);
            unsigned long long k3 = ((unsigned long long)v.w << 32) | (unsigned)(j4 + 3);
            unsigned long long m01 = k0 < k1 ? k0 : k1;
            unsigned long long m23 = k2 < k3 ? k2 : k3;
            unsigned long long mm = m01 < m23 ? m01 : m23;
            m = mm < m ? mm : m;
        }
        return m;
    };

    unsigned long long lm = scan();
    for (int k = 0; k < KK; ++k) {
        unsigned long long best = lm;
        #pragma unroll
        for (int s = 1; s < 64; s <<= 1) {
            unsigned long long ob = __shfl_xor(best, s, 64);
            best = ob < best ? ob : best;
        }
        int bi = (int)(unsigned)best;
        if (lane == 0) outp[k] = bi;
        if (lm == best) {           // exactly one winner lane (indices unique)
            drow[bi] = 0xFFFFFFFFu;
            lm = scan();            // same-wave LDS ops are in-order
        }
    }
}

// ---------------- projection GEMM: Z[m][0..2Co) = sum_c x[c][m] * Wstk[c][.] ----
template<int CIN, int CO2>
__global__ void __launch_bounds__(256)
proj_gemm(const float* __restrict__ x, long bst,
          const float* __restrict__ Wstk, float* __restrict__ Z) {
    const int tid = threadIdx.x;
    const int b  = blockIdx.x & 7;
    const int mt = (blockIdx.x >> 3) & 31;
    const int ot = blockIdx.x >> 8;
    const int mi = mt * 64 + (tid & 15) * 4;
    const int oj = ot * 64 + (tid >> 4) * 4;
    const float* xb = x + (long)b * bst + mi;

    float acc[4][4];
    #pragma unroll
    for (int r = 0; r < 4; ++r)
        #pragma unroll
        for (int j = 0; j < 4; ++j) acc[r][j] = 0.f;

    #pragma unroll 4
    for (int c = 0; c < CIN; ++c) {
        float4 xv = *(const float4*)(xb + (long)c * Nn);
        float4 wv = *(const float4*)(Wstk + (long)c * CO2 + oj);
        acc[0][0] += xv.x * wv.x; acc[0][1] += xv.x * wv.y; acc[0][2] += xv.x * wv.z; acc[0][3] += xv.x * wv.w;
        acc[1][0] += xv.y * wv.x; acc[1][1] += xv.y * wv.y; acc[1][2] += xv.y * wv.z; acc[1][3] += xv.y * wv.w;
        acc[2][0] += xv.z * wv.x; acc[2][1] += xv.z * wv.y; acc[2][2] += xv.z * wv.z; acc[2][3] += xv.z * wv.w;
        acc[3][0] += xv.w * wv.x; acc[3][1] += xv.w * wv.y; acc[3][2] += xv.w * wv.z; acc[3][3] += xv.w * wv.w;
    }
    float* Zb = Z + (long)b * 2048 * CO2;
    #pragma unroll
    for (int r = 0; r < 4; ++r) {
        float4 v = make_float4(acc[r][0], acc[r][1], acc[r][2], acc[r][3]);
        *(float4*)(Zb + (long)(mi + r) * CO2 + oj) = v;
    }
}

// ---------------- gather-max epilogue ----------------
template<int CO>
__global__ void __launch_bounds__(256)
gather_max(const float* __restrict__ Z, const int* __restrict__ idx,
           float* __restrict__ out, long obst) {
    constexpr int CO2 = 2 * CO;
    constexpr int VEC = CO / 64;
    __shared__ float tile[16][CO + 4];
    __shared__ int ji[16][KK];
    const int tid = threadIdx.x;
    const int b  = blockIdx.x & 7;
    const int n0 = (blockIdx.x >> 3) * 16;
    const float* Zb = Z + (long)b * 2048 * CO2;

    for (int t = tid; t < 16 * KK; t += 256) {
        int nn = t / KK, k = t - nn * KK;
        ji[nn][k] = idx[((long)b * Nn + n0 + nn) * KK + k];
    }
    __syncthreads();

    const int w = tid >> 6, lane = tid & 63;
    for (int i = 0; i < 4; ++i) {
        int nl = w * 4 + i, n = n0 + nl;
        float mx[VEC];
        #pragma unroll
        for (int v = 0; v < VEC; ++v) mx[v] = -FLT_MAX;
        for (int k = 0; k < KK; ++k) {
            int m = ji[nl][k];
            const float* zr = Zb + (long)m * CO2 + lane * VEC;
            #pragma unroll
            for (int v = 0; v < VEC; ++v) mx[v] = fmaxf(mx[v], zr[v]);
        }
        const float* zc = Zb + (long)n * CO2 + CO + lane * VEC;
        #pragma unroll
        for (int v = 0; v < VEC; ++v) {
            float y = mx[v] + zc[v];
            tile[nl][lane * VEC + v] = y > 0.f ? y : SLOPE * y;
        }
    }
    __syncthreads();

    for (int r = tid; r < CO * 4; r += 256) {
        int o = r >> 2, q = r & 3;
        float4 vv;
        vv.x = tile[q * 4 + 0][o];
        vv.y = tile[q * 4 + 1][o];
        vv.z = tile[q * 4 + 2][o];
        vv.w = tile[q * 4 + 3][o];
        *(float4*)(out + (long)b * obst + (long)o * Nn + n0 + q * 4) = vv;
    }
}

// ---------------- Global conv: register-blocked partial-max ----------------
// grid: B * 16 ot * 16 ch = 2048 blocks; 256 thr = 8 og x 32 ni; 128 n per block
__global__ void __launch_bounds__(256)
global_kernel(const float* __restrict__ xcat,
              const float* __restrict__ WgT,   // [512][1024]
              float* __restrict__ partial) {   // [B][1024][NCH]
    const int tid = threadIdx.x;
    const int og = tid >> 5;
    const int ni = tid & 31;
    const int b  = blockIdx.x >> 8;
    const int r  = blockIdx.x & 255;
    const int ot = r >> 4;
    const int ch = r & 15;
    const int obase = ot * 64 + og * 8;
    const float* xp = xcat + (long)b * 512 * Nn + ch * 128 + ni * 4;

    float acc[8][4];
    #pragma unroll
    for (int t = 0; t < 8; ++t)
        #pragma unroll
        for (int j = 0; j < 4; ++j) acc[t][j] = 0.f;

    #pragma unroll 2
    for (int c = 0; c < 512; ++c) {
        float4 w0 = *(const float4*)(WgT + (long)c * 1024 + obase);
        float4 w1 = *(const float4*)(WgT + (long)c * 1024 + obase + 4);
        float4 v  = *(const float4*)(xp + (long)c * Nn);
        acc[0][0] += w0.x * v.x; acc[0][1] += w0.x * v.y; acc[0][2] += w0.x * v.z; acc[0][3] += w0.x * v.w;
        acc[1][0] += w0.y * v.x; acc[1][1] += w0.y * v.y; acc[1][2] += w0.y * v.z; acc[1][3] += w0.y * v.w;
        acc[2][0] += w0.z * v.x; acc[2][1] += w0.z * v.y; acc[2][2] += w0.z * v.z; acc[2][3] += w0.z * v.w;
        acc[3][0] += w0.w * v.x; acc[3][1] += w0.w * v.y; acc[3][2] += w0.w * v.z; acc[3][3] += w0.w * v.w;
        acc[4][0] += w1.x * v.x; acc[4][1] += w1.x * v.y; acc[4][2] += w1.x * v.z; acc[4][3] += w1.x * v.w;
        acc[5][0] += w1.y * v.x; acc[5][1] += w1.y * v.y; acc[5][2] += w1.y * v.z; acc[5][3] += w1.y * v.w;
        acc[6][0] += w1.z * v.x; acc[6][1] += w1.z * v.y; acc[6][2] += w1.z * v.z; acc[6][3] += w1.z * v.w;
        acc[7][0] += w1.w * v.x; acc[7][1] += w1.w * v.y; acc[7][2] += w1.w * v.z; acc[7][3] += w1.w * v.w;
    }
    float m[8];
    #pragma unroll
    for (int t = 0; t < 8; ++t)
        m[t] = fmaxf(fmaxf(acc[t][0], acc[t][1]), fmaxf(acc[t][2], acc[t][3]));
    #pragma unroll
    for (int t = 0; t < 8; ++t) {
        float v = m[t];
        #pragma unroll
        for (int s = 16; s > 0; s >>= 1)
            v = fmaxf(v, __shfl_xor(v, s, 32));
        m[t] = v;
    }
    if (ni == 0) {
        #pragma unroll
        for (int t = 0; t < 8; ++t)
            partial[((long)b * 1024 + obase + t) * NCH + ch] = m[t];
    }
}

// ---------------- final max over n-chunks + leaky ----------------
__global__ void gmax_kernel(const float* __restrict__ partial, float* __restrict__ out) {
    int i = blockIdx.x * 256 + threadIdx.x;   // 0..8191
    float m = -FLT_MAX;
    #pragma unroll
    for (int j = 0; j < NCH; ++j) m = fmaxf(m, partial[(long)i * NCH + j]);
    out[i] = m > 0.f ? m : SLOPE * m;
}

extern "C" void kernel_launch(void* const* d_in, const int* in_sizes, int n_in,
                              void* d_out, int out_size, void* d_ws, size_t ws_size,
                              hipStream_t stream) {
    const float* x  = (const float*)d_in[0];
    const float* W1 = (const float*)d_in[1];   // [64][6]
    const float* W2 = (const float*)d_in[2];   // [64][128]
    const float* W3 = (const float*)d_in[3];   // [128][128]
    const float* W4 = (const float*)d_in[4];   // [256][256]
    const float* Wg = (const float*)d_in[5];   // [1024][512]
    float* out = (float*)d_out;

    float* ws = (float*)d_ws;
    float* xcat = ws;                                   // 8*512*2048
    int*   idxb = (int*)(xcat + (long)BB * 512 * Nn);   // 8*2048*20 ints
    float* wgt  = (float*)(idxb + (long)BB * Nn * KK);  // 512*1024
    float* part = wgt + 512 * 1024;                     // 8*1024*NCH
    float* ws1  = part + BB * 1024 * NCH;               // 3*128
    float* ws2  = ws1 + 3 * 128;                        // 64*128
    float* ws3  = ws2 + 64 * 128;                       // 64*256
    float* ws4  = ws3 + 64 * 256;                       // 128*512
    float* Z    = ws4 + 128 * 512;                      // 8*2048*512

    const long XB = (long)512 * Nn;   // xcat batch stride

    transpose_kernel<<<(1024 * 512 + 255) / 256, 256, 0, stream>>>(Wg, wgt, 1024, 512);
    wstack_kernel<<<(64 * 3 + 255) / 256, 256, 0, stream>>>(W1, ws1, 64, 3);
    wstack_kernel<<<(64 * 64 + 255) / 256, 256, 0, stream>>>(W2, ws2, 64, 64);
    wstack_kernel<<<(128 * 64 + 255) / 256, 256, 0, stream>>>(W3, ws3, 128, 64);
    wstack_kernel<<<(256 * 128 + 255) / 256, 256, 0, stream>>>(W4, ws4, 256, 128);

    const int knn_grid = BB * (Nn / 8);    // 2048 blocks, 512 threads
    const int ep_grid  = (Nn / 16) * BB;   // 1024

    // stage 1: x (C=3) -> xcat[0:64]
    knn_kernel<3><<<knn_grid, 512, 0, stream>>>(x, (long)3 * Nn, idxb);
    proj_gemm<3, 128><<<8 * 32 * 2, 256, 0, stream>>>(x, (long)3 * Nn, ws1, Z);
    gather_max<64><<<ep_grid, 256, 0, stream>>>(Z, idxb, xcat, XB);
    // stage 2: xcat[0:64] -> xcat[64:128]
    knn_kernel<64><<<knn_grid, 512, 0, stream>>>(xcat, XB, idxb);
    proj_gemm<64, 128><<<8 * 32 * 2, 256, 0, stream>>>(xcat, XB, ws2, Z);
    gather_max<64><<<ep_grid, 256, 0, stream>>>(Z, idxb, xcat + (long)64 * Nn, XB);
    // stage 3: xcat[64:128] -> xcat[128:256]
    knn_kernel<64><<<knn_grid, 512, 0, stream>>>(xcat + (long)64 * Nn, XB, idxb);
    proj_gemm<64, 256><<<8 * 32 * 4, 256, 0, stream>>>(xcat + (long)64 * Nn, XB, ws3, Z);
    gather_max<128><<<ep_grid, 256, 0, stream>>>(Z, idxb, xcat + (long)128 * Nn, XB);
    // stage 4: xcat[128:256] -> xcat[256:512]
    knn_kernel<128><<<knn_grid, 512, 0, stream>>>(xcat + (long)128 * Nn, XB, idxb);
    proj_gemm<128, 512><<<8 * 32 * 8, 256, 0, stream>>>(xcat + (long)128 * Nn, XB, ws4, Z);
    gather_max<256><<<ep_grid, 256, 0, stream>>>(Z, idxb, xcat + (long)256 * Nn, XB);

    // global conv (partial) + final max
    global_kernel<<<BB * 256, 256, 0, stream>>>(xcat, wgt, part);
    gmax_kernel<<<BB * 1024 / 256, 256, 0, stream>>>(part, out);
}

// Round 5
// 774.216 us; speedup vs baseline: 4.3229x; 1.4874x over previous
//
#include <hip/hip_runtime.h>
#include <hip/hip_bf16.h>
#include <cfloat>

#define Nn 2048
#define KK 20
#define BB 8
#define SLOPE 0.2f
#define NCH 32   // partial chunks in global conv (8 nblk x 4 waves)

typedef __bf16 bf16x8 __attribute__((ext_vector_type(8)));
typedef float f32x4 __attribute__((ext_vector_type(4)));

// ---------------- weight stack: Wstk[c][o] = W[o][c]; Wstk[c][Co+o] = W[o][C+c]-W[o][c]
__global__ void wstack_kernel(const float* __restrict__ W, float* __restrict__ Wstk,
                              int Co, int C) {
    int i = blockIdx.x * 256 + threadIdx.x;
    if (i < Co * C) {
        int o = i / C, c = i - o * C;
        float a = W[(long)o * 2 * C + c];
        float bb = W[(long)o * 2 * C + C + c];
        Wstk[(long)c * 2 * Co + o] = a;
        Wstk[(long)c * 2 * Co + Co + o] = bb - a;
    }
}

// ---------------- fp32 -> bf16 copy ----------------
__global__ void tobf16_kernel(const float* __restrict__ A, __hip_bfloat16* __restrict__ B,
                              int n) {
    int i = blockIdx.x * 256 + threadIdx.x;
    if (i < n) B[i] = __float2bfloat16(A[i]);
}

// order-preserving float-bits -> u32 map (works for negatives)
__device__ __forceinline__ unsigned fkey(float f) {
    unsigned u = __float_as_uint(f);
    return u ^ (((unsigned)((int)u >> 31)) | 0x80000000u);
}

// ---------------- KNN: 8 rows per block, 512 threads ----------------
// dist order == xx_j - 2*dot(x_n, x_j)  (per-row const xx_n dropped: order-invariant)
template<int C>
__global__ void __launch_bounds__(512)
knn_kernel(const float* __restrict__ x, long bstride, int* __restrict__ idx) {
    __shared__ unsigned dist[8][Nn];   // XOR-mapped float keys; 64 KB exactly
    const int tid = threadIdx.x;
    const int b  = blockIdx.x >> 8;         // Nn/8 = 256 blocks per b
    const int n0 = (blockIdx.x & 255) * 8;
    const float* xb = x + (long)b * bstride;

    // distance phase: thread owns j = q*512 + tid, q = 0..3
    float acc[8][4];
    #pragma unroll
    for (int r = 0; r < 8; ++r)
        #pragma unroll
        for (int q = 0; q < 4; ++q) acc[r][q] = 0.f;
    float sq[4] = {0.f, 0.f, 0.f, 0.f};

    #pragma unroll 4
    for (int c = 0; c < C; ++c) {
        const float* xp = xb + (long)c * Nn;
        float xv0 = xp[tid];
        float xv1 = xp[tid + 512];
        float xv2 = xp[tid + 1024];
        float xv3 = xp[tid + 1536];
        float4 c0 = *(const float4*)(xp + n0);
        float4 c1 = *(const float4*)(xp + n0 + 4);
        sq[0] += xv0 * xv0; sq[1] += xv1 * xv1; sq[2] += xv2 * xv2; sq[3] += xv3 * xv3;
        acc[0][0] += c0.x * xv0; acc[0][1] += c0.x * xv1; acc[0][2] += c0.x * xv2; acc[0][3] += c0.x * xv3;
        acc[1][0] += c0.y * xv0; acc[1][1] += c0.y * xv1; acc[1][2] += c0.y * xv2; acc[1][3] += c0.y * xv3;
        acc[2][0] += c0.z * xv0; acc[2][1] += c0.z * xv1; acc[2][2] += c0.z * xv2; acc[2][3] += c0.z * xv3;
        acc[3][0] += c0.w * xv0; acc[3][1] += c0.w * xv1; acc[3][2] += c0.w * xv2; acc[3][3] += c0.w * xv3;
        acc[4][0] += c1.x * xv0; acc[4][1] += c1.x * xv1; acc[4][2] += c1.x * xv2; acc[4][3] += c1.x * xv3;
        acc[5][0] += c1.y * xv0; acc[5][1] += c1.y * xv1; acc[5][2] += c1.y * xv2; acc[5][3] += c1.y * xv3;
        acc[6][0] += c1.z * xv0; acc[6][1] += c1.z * xv1; acc[6][2] += c1.z * xv2; acc[6][3] += c1.z * xv3;
        acc[7][0] += c1.w * xv0; acc[7][1] += c1.w * xv1; acc[7][2] += c1.w * xv2; acc[7][3] += c1.w * xv3;
    }
    #pragma unroll
    for (int r = 0; r < 8; ++r) {
        #pragma unroll
        for (int q = 0; q < 4; ++q) {
            float d = fmaf(-2.f, acc[r][q], sq[q]);
            dist[r][q * 512 + tid] = fkey(d);
        }
    }
    __syncthreads();

    // selection: wave w owns row w; lazy per-lane top-2 in registers.
    const int w = tid >> 6, lane = tid & 63;
    unsigned* drow = dist[w];
    int* outp = idx + ((long)b * Nn + n0 + w) * KK;

    auto scan2 = [&](unsigned long long& m1, unsigned long long& m2) {
        m1 = ~0ull; m2 = ~0ull;
        #pragma unroll
        for (int jj = 0; jj < 8; ++jj) {
            int j4 = (jj * 64 + lane) * 4;
            uint4 v = *(const uint4*)(drow + j4);
            unsigned long long kk0 = ((unsigned long long)v.x << 32) | (unsigned)(j4 + 0);
            unsigned long long kk1 = ((unsigned long long)v.y << 32) | (unsigned)(j4 + 1);
            unsigned long long kk2 = ((unsigned long long)v.z << 32) | (unsigned)(j4 + 2);
            unsigned long long kk3 = ((unsigned long long)v.w << 32) | (unsigned)(j4 + 3);
            unsigned long long hi;
            hi = kk0 > m1 ? kk0 : m1; m1 = kk0 < m1 ? kk0 : m1; m2 = hi < m2 ? hi : m2;
            hi = kk1 > m1 ? kk1 : m1; m1 = kk1 < m1 ? kk1 : m1; m2 = hi < m2 ? hi : m2;
            hi = kk2 > m1 ? kk2 : m1; m1 = kk2 < m1 ? kk2 : m1; m2 = hi < m2 ? hi : m2;
            hi = kk3 > m1 ? kk3 : m1; m1 = kk3 < m1 ? kk3 : m1; m2 = hi < m2 ? hi : m2;
        }
    };

    unsigned long long lm1, lm2;
    scan2(lm1, lm2);
    for (int k = 0; k < KK; ++k) {
        unsigned long long best = lm1;
        #pragma unroll
        for (int s = 1; s < 64; s <<= 1) {
            unsigned long long ob = __shfl_xor(best, s, 64);
            best = ob < best ? ob : best;
        }
        int bi = (int)(unsigned)best;
        if (lane == 0) outp[k] = bi;
        if (lm1 == best) {          // exactly one winner lane (idx in low bits -> unique)
            drow[bi] = 0xFFFFFFFFu; // consumed sentinel sorts after all genuine keys
            if (lm2 != ~0ull) { lm1 = lm2; lm2 = ~0ull; }
            else scan2(lm1, lm2);   // rare: lane's second win since last refill
        }
    }
}

// ---------------- projection GEMM: Z[m][0..2Co) = sum_c x[c][m] * Wstk[c][.] ----
template<int CIN, int CO2>
__global__ void __launch_bounds__(256)
proj_gemm(const float* __restrict__ x, long bst,
          const float* __restrict__ Wstk, float* __restrict__ Z) {
    const int tid = threadIdx.x;
    const int b  = blockIdx.x & 7;
    const int mt = (blockIdx.x >> 3) & 31;
    const int ot = blockIdx.x >> 8;
    const int mi = mt * 64 + (tid & 15) * 4;
    const int oj = ot * 64 + (tid >> 4) * 4;
    const float* xb = x + (long)b * bst + mi;

    float acc[4][4];
    #pragma unroll
    for (int r = 0; r < 4; ++r)
        #pragma unroll
        for (int j = 0; j < 4; ++j) acc[r][j] = 0.f;

    #pragma unroll 4
    for (int c = 0; c < CIN; ++c) {
        float4 xv = *(const float4*)(xb + (long)c * Nn);
        float4 wv = *(const float4*)(Wstk + (long)c * CO2 + oj);
        acc[0][0] += xv.x * wv.x; acc[0][1] += xv.x * wv.y; acc[0][2] += xv.x * wv.z; acc[0][3] += xv.x * wv.w;
        acc[1][0] += xv.y * wv.x; acc[1][1] += xv.y * wv.y; acc[1][2] += xv.y * wv.z; acc[1][3] += xv.y * wv.w;
        acc[2][0] += xv.z * wv.x; acc[2][1] += xv.z * wv.y; acc[2][2] += xv.z * wv.z; acc[2][3] += xv.z * wv.w;
        acc[3][0] += xv.w * wv.x; acc[3][1] += xv.w * wv.y; acc[3][2] += xv.w * wv.z; acc[3][3] += xv.w * wv.w;
    }
    float* Zb = Z + (long)b * 2048 * CO2;
    #pragma unroll
    for (int r = 0; r < 4; ++r) {
        float4 v = make_float4(acc[r][0], acc[r][1], acc[r][2], acc[r][3]);
        *(float4*)(Zb + (long)(mi + r) * CO2 + oj) = v;
    }
}

// ---------------- gather-max epilogue (also emits bf16 n-major copy) ----------------
template<int CO>
__global__ void __launch_bounds__(256)
gather_max(const float* __restrict__ Z, const int* __restrict__ idx,
           float* __restrict__ out, long obst,
           __hip_bfloat16* __restrict__ xbT, int coff) {
    constexpr int CO2 = 2 * CO;
    constexpr int VEC = CO / 64;
    __shared__ float tile[16][CO + 4];
    __shared__ int ji[16][KK];
    const int tid = threadIdx.x;
    const int b  = blockIdx.x & 7;
    const int n0 = (blockIdx.x >> 3) * 16;
    const float* Zb = Z + (long)b * 2048 * CO2;

    for (int t = tid; t < 16 * KK; t += 256) {
        int nn = t / KK, k = t - nn * KK;
        ji[nn][k] = idx[((long)b * Nn + n0 + nn) * KK + k];
    }
    __syncthreads();

    const int w = tid >> 6, lane = tid & 63;
    for (int i = 0; i < 4; ++i) {
        int nl = w * 4 + i, n = n0 + nl;
        float mx[VEC];
        #pragma unroll
        for (int v = 0; v < VEC; ++v) mx[v] = -FLT_MAX;
        for (int k = 0; k < KK; ++k) {
            int m = ji[nl][k];
            const float* zr = Zb + (long)m * CO2 + lane * VEC;
            #pragma unroll
            for (int v = 0; v < VEC; ++v) mx[v] = fmaxf(mx[v], zr[v]);
        }
        const float* zc = Zb + (long)n * CO2 + CO + lane * VEC;
        __hip_bfloat16* xr = xbT + ((long)b * 2048 + n) * 512 + coff + lane * VEC;
        #pragma unroll
        for (int v = 0; v < VEC; ++v) {
            float y = mx[v] + zc[v];
            y = y > 0.f ? y : SLOPE * y;
            tile[nl][lane * VEC + v] = y;
            xr[v] = __float2bfloat16(y);
        }
    }
    __syncthreads();

    for (int r = tid; r < CO * 4; r += 256) {
        int o = r >> 2, q = r & 3;
        float4 vv;
        vv.x = tile[q * 4 + 0][o];
        vv.y = tile[q * 4 + 1][o];
        vv.z = tile[q * 4 + 2][o];
        vv.w = tile[q * 4 + 3][o];
        *(float4*)(out + (long)b * obst + (long)o * Nn + n0 + q * 4) = vv;
    }
}

// ---------------- Global conv via bf16 MFMA, fused max-over-n ----------------
// grid: B(8) x 16 o-tiles(64) x 8 n-blocks(256) = 1024; 256 thr = 4 waves x 64 n each.
// A[m][k] = Wgb[o0+m][k] (row-major); B[k][n] = xbT[n][k] (n-major).
__global__ void __launch_bounds__(256)
global_mfma(const __hip_bfloat16* __restrict__ Wgb,   // [1024][512]
            const __hip_bfloat16* __restrict__ xbT,   // [B][2048][512]
            float* __restrict__ partial) {            // [B][1024][NCH]
    const int tid = threadIdx.x;
    const int w = tid >> 6, lane = tid & 63;
    const int lm = lane & 15, quad = lane >> 4;
    const int b  = blockIdx.x >> 7;
    const int ot = (blockIdx.x >> 3) & 15;
    const int nb = blockIdx.x & 7;
    const int o0 = ot * 64;
    const int nbw = nb * 256 + w * 64;

    const __hip_bfloat16* Arow = Wgb + (long)(o0 + lm) * 512 + quad * 8;
    const __hip_bfloat16* Brow = xbT + ((long)b * 2048 + nbw + lm) * 512 + quad * 8;

    f32x4 acc[4][4];
    #pragma unroll
    for (int mt = 0; mt < 4; ++mt)
        #pragma unroll
        for (int nt = 0; nt < 4; ++nt)
            acc[mt][nt] = (f32x4){0.f, 0.f, 0.f, 0.f};

    #pragma unroll 2
    for (int kk = 0; kk < 512; kk += 32) {
        bf16x8 a[4], bb[4];
        #pragma unroll
        for (int mt = 0; mt < 4; ++mt)
            a[mt] = *(const bf16x8*)(const void*)(Arow + (long)mt * 16 * 512 + kk);
        #pragma unroll
        for (int nt = 0; nt < 4; ++nt)
            bb[nt] = *(const bf16x8*)(const void*)(Brow + (long)nt * 16 * 512 + kk);
        #pragma unroll
        for (int mt = 0; mt < 4; ++mt)
            #pragma unroll
            for (int nt = 0; nt < 4; ++nt)
                acc[mt][nt] = __builtin_amdgcn_mfma_f32_16x16x32_bf16(
                    a[mt], bb[nt], acc[mt][nt], 0, 0, 0);
    }

    // D mapping: col(n) = lane&15, row(m) = quad*4 + reg
    #pragma unroll
    for (int mt = 0; mt < 4; ++mt) {
        #pragma unroll
        for (int r = 0; r < 4; ++r) {
            float v = fmaxf(fmaxf(acc[mt][0][r], acc[mt][1][r]),
                            fmaxf(acc[mt][2][r], acc[mt][3][r]));
            #pragma unroll
            for (int s = 1; s < 16; s <<= 1)
                v = fmaxf(v, __shfl_xor(v, s, 16));
            if (lm == 0) {
                int o = o0 + mt * 16 + quad * 4 + r;
                partial[((long)b * 1024 + o) * NCH + nb * 4 + w] = v;
            }
        }
    }
}

// ---------------- final max over chunks + leaky ----------------
__global__ void gmax_kernel(const float* __restrict__ partial, float* __restrict__ out) {
    int i = blockIdx.x * 256 + threadIdx.x;   // 0..8191
    float m = -FLT_MAX;
    #pragma unroll
    for (int j = 0; j < NCH; ++j) m = fmaxf(m, partial[(long)i * NCH + j]);
    out[i] = m > 0.f ? m : SLOPE * m;
}

extern "C" void kernel_launch(void* const* d_in, const int* in_sizes, int n_in,
                              void* d_out, int out_size, void* d_ws, size_t ws_size,
                              hipStream_t stream) {
    const float* x  = (const float*)d_in[0];
    const float* W1 = (const float*)d_in[1];   // [64][6]
    const float* W2 = (const float*)d_in[2];   // [64][128]
    const float* W3 = (const float*)d_in[3];   // [128][128]
    const float* W4 = (const float*)d_in[4];   // [256][256]
    const float* Wg = (const float*)d_in[5];   // [1024][512]
    float* out = (float*)d_out;

    float* ws = (float*)d_ws;
    float* xcat = ws;                                       // 8*512*2048 f32
    int*   idxb = (int*)(xcat + (long)BB * 512 * Nn);       // 8*2048*20 int
    float* part = (float*)(idxb + (long)BB * Nn * KK);      // 8*1024*NCH f32
    float* ws1  = part + (long)BB * 1024 * NCH;             // 3*128
    float* ws2  = ws1 + 3 * 128;                            // 64*128
    float* ws3  = ws2 + 64 * 128;                           // 64*256
    float* ws4  = ws3 + 64 * 256;                           // 128*512
    __hip_bfloat16* Wgb = (__hip_bfloat16*)(ws4 + 128 * 512);   // 1024*512 bf16
    __hip_bfloat16* xbT = Wgb + (long)1024 * 512;               // 8*2048*512 bf16
    float* Z    = (float*)(xbT + (long)BB * Nn * 512);          // 8*2048*512 f32

    const long XB = (long)512 * Nn;   // xcat batch stride

    wstack_kernel<<<(64 * 3 + 255) / 256, 256, 0, stream>>>(W1, ws1, 64, 3);
    wstack_kernel<<<(64 * 64 + 255) / 256, 256, 0, stream>>>(W2, ws2, 64, 64);
    wstack_kernel<<<(128 * 64 + 255) / 256, 256, 0, stream>>>(W3, ws3, 128, 64);
    wstack_kernel<<<(256 * 128 + 255) / 256, 256, 0, stream>>>(W4, ws4, 256, 128);
    tobf16_kernel<<<(1024 * 512 + 255) / 256, 256, 0, stream>>>(Wg, Wgb, 1024 * 512);

    const int knn_grid = BB * (Nn / 8);    // 2048 blocks, 512 threads
    const int ep_grid  = (Nn / 16) * BB;   // 1024

    // stage 1: x (C=3) -> xcat[0:64], xbT[:, 0:64)
    knn_kernel<3><<<knn_grid, 512, 0, stream>>>(x, (long)3 * Nn, idxb);
    proj_gemm<3, 128><<<8 * 32 * 2, 256, 0, stream>>>(x, (long)3 * Nn, ws1, Z);
    gather_max<64><<<ep_grid, 256, 0, stream>>>(Z, idxb, xcat, XB, xbT, 0);
    // stage 2
    knn_kernel<64><<<knn_grid, 512, 0, stream>>>(xcat, XB, idxb);
    proj_gemm<64, 128><<<8 * 32 * 2, 256, 0, stream>>>(xcat, XB, ws2, Z);
    gather_max<64><<<ep_grid, 256, 0, stream>>>(Z, idxb, xcat + (long)64 * Nn, XB, xbT, 64);
    // stage 3
    knn_kernel<64><<<knn_grid, 512, 0, stream>>>(xcat + (long)64 * Nn, XB, idxb);
    proj_gemm<64, 256><<<8 * 32 * 4, 256, 0, stream>>>(xcat + (long)64 * Nn, XB, ws3, Z);
    gather_max<128><<<ep_grid, 256, 0, stream>>>(Z, idxb, xcat + (long)128 * Nn, XB, xbT, 128);
    // stage 4
    knn_kernel<128><<<knn_grid, 512, 0, stream>>>(xcat + (long)128 * Nn, XB, idxb);
    proj_gemm<128, 512><<<8 * 32 * 8, 256, 0, stream>>>(xcat + (long)128 * Nn, XB, ws4, Z);
    gather_max<256><<<ep_grid, 256, 0, stream>>>(Z, idxb, xcat + (long)256 * Nn, XB, xbT, 256);

    // global conv via MFMA (fused max) + final reduce
    global_mfma<<<BB * 16 * 8, 256, 0, stream>>>(Wgb, xbT, part);
    gmax_kernel<<<BB * 1024 / 256, 256, 0, stream>>>(part, out);
}

// Round 6
// 751.460 us; speedup vs baseline: 4.4538x; 1.0303x over previous
//
#include <hip/hip_runtime.h>
#include <hip/hip_bf16.h>
#include <cfloat>

#define Nn 2048
#define KK 20
#define BB 8
#define SLOPE 0.2f
#define NCH 32   // partial chunks in global conv (8 nblk x 4 waves)

typedef __bf16 bf16x8 __attribute__((ext_vector_type(8)));
typedef float f32x4 __attribute__((ext_vector_type(4)));

// ---------------- weight stack: Wstk[c][o] = W[o][c]; Wstk[c][Co+o] = W[o][C+c]-W[o][c]
__global__ void wstack_kernel(const float* __restrict__ W, float* __restrict__ Wstk,
                              int Co, int C) {
    int i = blockIdx.x * 256 + threadIdx.x;
    if (i < Co * C) {
        int o = i / C, c = i - o * C;
        float a = W[(long)o * 2 * C + c];
        float bb = W[(long)o * 2 * C + C + c];
        Wstk[(long)c * 2 * Co + o] = a;
        Wstk[(long)c * 2 * Co + Co + o] = bb - a;
    }
}

// ---------------- fp32 -> bf16 copy ----------------
__global__ void tobf16_kernel(const float* __restrict__ A, __hip_bfloat16* __restrict__ B,
                              int n) {
    int i = blockIdx.x * 256 + threadIdx.x;
    if (i < n) B[i] = __float2bfloat16(A[i]);
}

// order-preserving float-bits -> u32 map (works for negatives)
__device__ __forceinline__ unsigned fkey(float f) {
    unsigned u = __float_as_uint(f);
    return u ^ (((unsigned)((int)u >> 31)) | 0x80000000u);
}

// ---------------- KNN: 8 rows per block, 512 threads ----------------
// dist order == xx_j - 2*dot(x_n, x_j)  (per-row const xx_n dropped: order-invariant)
template<int C>
__global__ void __launch_bounds__(512)
knn_kernel(const float* __restrict__ x, long bstride, int* __restrict__ idx) {
    __shared__ unsigned dist[8][Nn];   // XOR-mapped float keys; 64 KB exactly
    const int tid = threadIdx.x;
    const int b  = blockIdx.x >> 8;         // Nn/8 = 256 blocks per b
    const int n0 = (blockIdx.x & 255) * 8;
    const float* xb = x + (long)b * bstride;

    // distance phase: thread owns j = q*512 + tid, q = 0..3
    float acc[8][4];
    #pragma unroll
    for (int r = 0; r < 8; ++r)
        #pragma unroll
        for (int q = 0; q < 4; ++q) acc[r][q] = 0.f;
    float sq[4] = {0.f, 0.f, 0.f, 0.f};

    #pragma unroll 4
    for (int c = 0; c < C; ++c) {
        const float* xp = xb + (long)c * Nn;
        float xv0 = xp[tid];
        float xv1 = xp[tid + 512];
        float xv2 = xp[tid + 1024];
        float xv3 = xp[tid + 1536];
        float4 c0 = *(const float4*)(xp + n0);      // block-uniform -> scalar pipe
        float4 c1 = *(const float4*)(xp + n0 + 4);
        sq[0] += xv0 * xv0; sq[1] += xv1 * xv1; sq[2] += xv2 * xv2; sq[3] += xv3 * xv3;
        acc[0][0] += c0.x * xv0; acc[0][1] += c0.x * xv1; acc[0][2] += c0.x * xv2; acc[0][3] += c0.x * xv3;
        acc[1][0] += c0.y * xv0; acc[1][1] += c0.y * xv1; acc[1][2] += c0.y * xv2; acc[1][3] += c0.y * xv3;
        acc[2][0] += c0.z * xv0; acc[2][1] += c0.z * xv1; acc[2][2] += c0.z * xv2; acc[2][3] += c0.z * xv3;
        acc[3][0] += c0.w * xv0; acc[3][1] += c0.w * xv1; acc[3][2] += c0.w * xv2; acc[3][3] += c0.w * xv3;
        acc[4][0] += c1.x * xv0; acc[4][1] += c1.x * xv1; acc[4][2] += c1.x * xv2; acc[4][3] += c1.x * xv3;
        acc[5][0] += c1.y * xv0; acc[5][1] += c1.y * xv1; acc[5][2] += c1.y * xv2; acc[5][3] += c1.y * xv3;
        acc[6][0] += c1.z * xv0; acc[6][1] += c1.z * xv1; acc[6][2] += c1.z * xv2; acc[6][3] += c1.z * xv3;
        acc[7][0] += c1.w * xv0; acc[7][1] += c1.w * xv1; acc[7][2] += c1.w * xv2; acc[7][3] += c1.w * xv3;
    }
    #pragma unroll
    for (int r = 0; r < 8; ++r) {
        #pragma unroll
        for (int q = 0; q < 4; ++q) {
            float d = fmaf(-2.f, acc[r][q], sq[q]);
            dist[r][q * 512 + tid] = fkey(d);
        }
    }
    __syncthreads();

    // selection: wave w owns row w; lazy per-lane top-2 in registers.
    // Per round: u32 min butterfly + ballot winner-lane + u32 index broadcast.
    const int w = tid >> 6, lane = tid & 63;
    unsigned* drow = dist[w];
    int* outp = idx + ((long)b * Nn + n0 + w) * KK;

    auto scan2 = [&](unsigned long long& m1, unsigned long long& m2) {
        m1 = ~0ull; m2 = ~0ull;
        #pragma unroll
        for (int jj = 0; jj < 8; ++jj) {
            int j4 = (jj * 64 + lane) * 4;
            uint4 v = *(const uint4*)(drow + j4);
            unsigned long long kk0 = ((unsigned long long)v.x << 32) | (unsigned)(j4 + 0);
            unsigned long long kk1 = ((unsigned long long)v.y << 32) | (unsigned)(j4 + 1);
            unsigned long long kk2 = ((unsigned long long)v.z << 32) | (unsigned)(j4 + 2);
            unsigned long long kk3 = ((unsigned long long)v.w << 32) | (unsigned)(j4 + 3);
            unsigned long long hi;
            hi = kk0 > m1 ? kk0 : m1; m1 = kk0 < m1 ? kk0 : m1; m2 = hi < m2 ? hi : m2;
            hi = kk1 > m1 ? kk1 : m1; m1 = kk1 < m1 ? kk1 : m1; m2 = hi < m2 ? hi : m2;
            hi = kk2 > m1 ? kk2 : m1; m1 = kk2 < m1 ? kk2 : m1; m2 = hi < m2 ? hi : m2;
            hi = kk3 > m1 ? kk3 : m1; m1 = kk3 < m1 ? kk3 : m1; m2 = hi < m2 ? hi : m2;
        }
    };

    unsigned long long lm1, lm2;
    scan2(lm1, lm2);
    for (int k = 0; k < KK; ++k) {
        unsigned key = (unsigned)(lm1 >> 32);
        unsigned bk = key;
        #pragma unroll
        for (int s = 1; s < 64; s <<= 1) {
            unsigned ob = __shfl_xor(bk, s, 64);
            bk = ob < bk ? ob : bk;
        }
        unsigned long long winners = __ballot(key == bk);
        int wl = (int)(__ffsll((unsigned long long)winners) - 1);
        int bi = (int)__shfl((unsigned)lm1, wl, 64);   // winner's j (low 32 bits)
        if (lane == 0) outp[k] = bi;
        if (lane == wl) {
            drow[bi] = 0xFFFFFFFFu;  // consumed sentinel (keeps refills correct)
            if (lm2 != ~0ull) { lm1 = lm2; lm2 = ~0ull; }
            else scan2(lm1, lm2);    // rare: lane's 3rd+ win since last refill
        }
    }
}

// ---------------- projection GEMM: Z[m][0..2Co) = sum_c x[c][m] * Wstk[c][.] ----
template<int CIN, int CO2>
__global__ void __launch_bounds__(256)
proj_gemm(const float* __restrict__ x, long bst,
          const float* __restrict__ Wstk, float* __restrict__ Z) {
    const int tid = threadIdx.x;
    const int b  = blockIdx.x & 7;
    const int mt = (blockIdx.x >> 3) & 31;
    const int ot = blockIdx.x >> 8;
    const int mi = mt * 64 + (tid & 15) * 4;
    const int oj = ot * 64 + (tid >> 4) * 4;
    const float* xb = x + (long)b * bst + mi;

    float acc[4][4];
    #pragma unroll
    for (int r = 0; r < 4; ++r)
        #pragma unroll
        for (int j = 0; j < 4; ++j) acc[r][j] = 0.f;

    #pragma unroll 4
    for (int c = 0; c < CIN; ++c) {
        float4 xv = *(const float4*)(xb + (long)c * Nn);
        float4 wv = *(const float4*)(Wstk + (long)c * CO2 + oj);
        acc[0][0] += xv.x * wv.x; acc[0][1] += xv.x * wv.y; acc[0][2] += xv.x * wv.z; acc[0][3] += xv.x * wv.w;
        acc[1][0] += xv.y * wv.x; acc[1][1] += xv.y * wv.y; acc[1][2] += xv.y * wv.z; acc[1][3] += xv.y * wv.w;
        acc[2][0] += xv.z * wv.x; acc[2][1] += xv.z * wv.y; acc[2][2] += xv.z * wv.z; acc[2][3] += xv.z * wv.w;
        acc[3][0] += xv.w * wv.x; acc[3][1] += xv.w * wv.y; acc[3][2] += xv.w * wv.z; acc[3][3] += xv.w * wv.w;
    }
    float* Zb = Z + (long)b * 2048 * CO2;
    #pragma unroll
    for (int r = 0; r < 4; ++r) {
        float4 v = make_float4(acc[r][0], acc[r][1], acc[r][2], acc[r][3]);
        *(float4*)(Zb + (long)(mi + r) * CO2 + oj) = v;
    }
}

// ---------------- gather-max epilogue (also emits bf16 n-major copy) ----------------
template<int CO>
__global__ void __launch_bounds__(256)
gather_max(const float* __restrict__ Z, const int* __restrict__ idx,
           float* __restrict__ out, long obst,
           __hip_bfloat16* __restrict__ xbT, int coff) {
    constexpr int CO2 = 2 * CO;
    constexpr int VEC = CO / 64;
    __shared__ float tile[16][CO + 4];
    __shared__ int ji[16][KK];
    const int tid = threadIdx.x;
    const int b  = blockIdx.x & 7;
    const int n0 = (blockIdx.x >> 3) * 16;
    const float* Zb = Z + (long)b * 2048 * CO2;

    for (int t = tid; t < 16 * KK; t += 256) {
        int nn = t / KK, k = t - nn * KK;
        ji[nn][k] = idx[((long)b * Nn + n0 + nn) * KK + k];
    }
    __syncthreads();

    const int w = tid >> 6, lane = tid & 63;
    for (int i = 0; i < 4; ++i) {
        int nl = w * 4 + i, n = n0 + nl;
        float mx[VEC];
        #pragma unroll
        for (int v = 0; v < VEC; ++v) mx[v] = -FLT_MAX;
        for (int k = 0; k < KK; ++k) {
            int m = ji[nl][k];
            const float* zr = Zb + (long)m * CO2 + lane * VEC;
            #pragma unroll
            for (int v = 0; v < VEC; ++v) mx[v] = fmaxf(mx[v], zr[v]);
        }
        const float* zc = Zb + (long)n * CO2 + CO + lane * VEC;
        __hip_bfloat16* xr = xbT + ((long)b * 2048 + n) * 512 + coff + lane * VEC;
        #pragma unroll
        for (int v = 0; v < VEC; ++v) {
            float y = mx[v] + zc[v];
            y = y > 0.f ? y : SLOPE * y;
            tile[nl][lane * VEC + v] = y;
            xr[v] = __float2bfloat16(y);
        }
    }
    __syncthreads();

    for (int r = tid; r < CO * 4; r += 256) {
        int o = r >> 2, q = r & 3;
        float4 vv;
        vv.x = tile[q * 4 + 0][o];
        vv.y = tile[q * 4 + 1][o];
        vv.z = tile[q * 4 + 2][o];
        vv.w = tile[q * 4 + 3][o];
        *(float4*)(out + (long)b * obst + (long)o * Nn + n0 + q * 4) = vv;
    }
}

// ---------------- Global conv via bf16 MFMA, fused max-over-n ----------------
__global__ void __launch_bounds__(256)
global_mfma(const __hip_bfloat16* __restrict__ Wgb,   // [1024][512]
            const __hip_bfloat16* __restrict__ xbT,   // [B][2048][512]
            float* __restrict__ partial) {            // [B][1024][NCH]
    const int tid = threadIdx.x;
    const int w = tid >> 6, lane = tid & 63;
    const int lm = lane & 15, quad = lane >> 4;
    const int b  = blockIdx.x >> 7;
    const int ot = (blockIdx.x >> 3) & 15;
    const int nb = blockIdx.x & 7;
    const int o0 = ot * 64;
    const int nbw = nb * 256 + w * 64;

    const __hip_bfloat16* Arow = Wgb + (long)(o0 + lm) * 512 + quad * 8;
    const __hip_bfloat16* Brow = xbT + ((long)b * 2048 + nbw + lm) * 512 + quad * 8;

    f32x4 acc[4][4];
    #pragma unroll
    for (int mt = 0; mt < 4; ++mt)
        #pragma unroll
        for (int nt = 0; nt < 4; ++nt)
            acc[mt][nt] = (f32x4){0.f, 0.f, 0.f, 0.f};

    #pragma unroll 2
    for (int kk = 0; kk < 512; kk += 32) {
        bf16x8 a[4], bb[4];
        #pragma unroll
        for (int mt = 0; mt < 4; ++mt)
            a[mt] = *(const bf16x8*)(const void*)(Arow + (long)mt * 16 * 512 + kk);
        #pragma unroll
        for (int nt = 0; nt < 4; ++nt)
            bb[nt] = *(const bf16x8*)(const void*)(Brow + (long)nt * 16 * 512 + kk);
        #pragma unroll
        for (int mt = 0; mt < 4; ++mt)
            #pragma unroll
            for (int nt = 0; nt < 4; ++nt)
                acc[mt][nt] = __builtin_amdgcn_mfma_f32_16x16x32_bf16(
                    a[mt], bb[nt], acc[mt][nt], 0, 0, 0);
    }

    // D mapping: col(n) = lane&15, row(m) = quad*4 + reg
    #pragma unroll
    for (int mt = 0; mt < 4; ++mt) {
        #pragma unroll
        for (int r = 0; r < 4; ++r) {
            float v = fmaxf(fmaxf(acc[mt][0][r], acc[mt][1][r]),
                            fmaxf(acc[mt][2][r], acc[mt][3][r]));
            #pragma unroll
            for (int s = 1; s < 16; s <<= 1)
                v = fmaxf(v, __shfl_xor(v, s, 16));
            if (lm == 0) {
                int o = o0 + mt * 16 + quad * 4 + r;
                partial[((long)b * 1024 + o) * NCH + nb * 4 + w] = v;
            }
        }
    }
}

// ---------------- final max over chunks + leaky ----------------
__global__ void gmax_kernel(const float* __restrict__ partial, float* __restrict__ out) {
    int i = blockIdx.x * 256 + threadIdx.x;   // 0..8191
    float m = -FLT_MAX;
    #pragma unroll
    for (int j = 0; j < NCH; ++j) m = fmaxf(m, partial[(long)i * NCH + j]);
    out[i] = m > 0.f ? m : SLOPE * m;
}

extern "C" void kernel_launch(void* const* d_in, const int* in_sizes, int n_in,
                              void* d_out, int out_size, void* d_ws, size_t ws_size,
                              hipStream_t stream) {
    const float* x  = (const float*)d_in[0];
    const float* W1 = (const float*)d_in[1];   // [64][6]
    const float* W2 = (const float*)d_in[2];   // [64][128]
    const float* W3 = (const float*)d_in[3];   // [128][128]
    const float* W4 = (const float*)d_in[4];   // [256][256]
    const float* Wg = (const float*)d_in[5];   // [1024][512]
    float* out = (float*)d_out;

    float* ws = (float*)d_ws;
    float* xcat = ws;                                       // 8*512*2048 f32
    int*   idxb = (int*)(xcat + (long)BB * 512 * Nn);       // 8*2048*20 int
    float* part = (float*)(idxb + (long)BB * Nn * KK);      // 8*1024*NCH f32
    float* ws1  = part + (long)BB * 1024 * NCH;             // 3*128
    float* ws2  = ws1 + 3 * 128;                            // 64*128
    float* ws3  = ws2 + 64 * 128;                           // 64*256
    float* ws4  = ws3 + 64 * 256;                           // 128*512
    __hip_bfloat16* Wgb = (__hip_bfloat16*)(ws4 + 128 * 512);   // 1024*512 bf16
    __hip_bfloat16* xbT = Wgb + (long)1024 * 512;               // 8*2048*512 bf16
    float* Z    = (float*)(xbT + (long)BB * Nn * 512);          // 8*2048*512 f32

    const long XB = (long)512 * Nn;   // xcat batch stride

    wstack_kernel<<<(64 * 3 + 255) / 256, 256, 0, stream>>>(W1, ws1, 64, 3);
    wstack_kernel<<<(64 * 64 + 255) / 256, 256, 0, stream>>>(W2, ws2, 64, 64);
    wstack_kernel<<<(128 * 64 + 255) / 256, 256, 0, stream>>>(W3, ws3, 128, 64);
    wstack_kernel<<<(256 * 128 + 255) / 256, 256, 0, stream>>>(W4, ws4, 256, 128);
    tobf16_kernel<<<(1024 * 512 + 255) / 256, 256, 0, stream>>>(Wg, Wgb, 1024 * 512);

    const int knn_grid = BB * (Nn / 8);    // 2048 blocks, 512 threads
    const int ep_grid  = (Nn / 16) * BB;   // 1024

    // stage 1: x (C=3) -> xcat[0:64], xbT[:, 0:64)
    knn_kernel<3><<<knn_grid, 512, 0, stream>>>(x, (long)3 * Nn, idxb);
    proj_gemm<3, 128><<<8 * 32 * 2, 256, 0, stream>>>(x, (long)3 * Nn, ws1, Z);
    gather_max<64><<<ep_grid, 256, 0, stream>>>(Z, idxb, xcat, XB, xbT, 0);
    // stage 2
    knn_kernel<64><<<knn_grid, 512, 0, stream>>>(xcat, XB, idxb);
    proj_gemm<64, 128><<<8 * 32 * 2, 256, 0, stream>>>(xcat, XB, ws2, Z);
    gather_max<64><<<ep_grid, 256, 0, stream>>>(Z, idxb, xcat + (long)64 * Nn, XB, xbT, 64);
    // stage 3
    knn_kernel<64><<<knn_grid, 512, 0, stream>>>(xcat + (long)64 * Nn, XB, idxb);
    proj_gemm<64, 256><<<8 * 32 * 4, 256, 0, stream>>>(xcat + (long)64 * Nn, XB, ws3, Z);
    gather_max<128><<<ep_grid, 256, 0, stream>>>(Z, idxb, xcat + (long)128 * Nn, XB, xbT, 128);
    // stage 4
    knn_kernel<128><<<knn_grid, 512, 0, stream>>>(xcat + (long)128 * Nn, XB, idxb);
    proj_gemm<128, 512><<<8 * 32 * 8, 256, 0, stream>>>(xcat + (long)128 * Nn, XB, ws4, Z);
    gather_max<256><<<ep_grid, 256, 0, stream>>>(Z, idxb, xcat + (long)256 * Nn, XB, xbT, 256);

    // global conv via MFMA (fused max) + final reduce
    global_mfma<<<BB * 16 * 8, 256, 0, stream>>>(Wgb, xbT, part);
    gmax_kernel<<<BB * 1024 / 256, 256, 0, stream>>>(part, out);
}